// Round 16
// baseline (716.959 us; speedup 1.0000x reference)
//
#include <hip/hip_runtime.h>
#include <cmath>

// ---------------- constants ----------------
constexpr int BB    = 8;     // batch
constexpr int LS    = 57;    // spectra tokens
constexpr int LG    = 9;     // gaia tokens
constexpr int RS    = BB*LS; // 456
constexpr int RG    = BB*LG; // 72
constexpr int DM    = 512;   // d_model
constexpr int DPROJ = 2320;
constexpr int DIN   = 1024;
constexpr int NH    = 16;    // mamba heads
constexpr int HD    = 64;    // mamba headdim
constexpr int NLAY  = 10;

constexpr int SP_IN  = 2;    // split-K for in-proj  (K=512  -> 256/split)
constexpr int SP_OUT = 4;    // split-K for out-proj (K=1024 -> 256/split)
constexpr int SP_ATT = 4;    // split-K for attention gemms (K=512 -> 128/split)

// tiled weight geometry: [kt2][nt2][64 n][32 k], 2048 shorts (4KB) per tile
constexpr int NT_IN  = 37;   // in-proj n-tiles (2320 -> padded 2368)
constexpr int NT_OUT = 8;    // out-proj n-tiles (512)
constexpr int NT_ATT = 8;    // attention n-tiles (512)
constexpr size_t WIN_PLANE  = (size_t)16*NT_IN*2048;   // K=512 -> 16 k-tiles
constexpr size_t WOUT_PLANE = (size_t)32*NT_OUT*2048;  // K=1024 -> 32 k-tiles
constexpr size_t ATT_PLANE  = (size_t)16*NT_ATT*2048;  // 512x512

__device__ __forceinline__ float siluf(float x){ return x / (1.f + expf(-x)); }

// ---------------- bf16 split helpers ----------------
typedef short  short8  __attribute__((ext_vector_type(8)));
typedef short  short4_ __attribute__((ext_vector_type(4)));
typedef float  f32x4   __attribute__((ext_vector_type(4)));

__device__ __forceinline__ unsigned short f2bh(float f){
    unsigned int u = __float_as_uint(f);
    u = u + 0x7FFFu + ((u >> 16) & 1u);
    return (unsigned short)(u >> 16);
}
__device__ __forceinline__ float bh2f(unsigned short h){
    return __uint_as_float(((unsigned int)h) << 16);
}

// ---------------- tokenize both modalities (+bf16 planes) ----------------
__global__ __launch_bounds__(512) void tokenize2(
    const float* __restrict__ xS, const float* __restrict__ wS, const float* __restrict__ bS,
    float* __restrict__ oS, unsigned short* __restrict__ oSh, unsigned short* __restrict__ oSl,
    const float* __restrict__ xG, const float* __restrict__ wG, const float* __restrict__ bG,
    float* __restrict__ oG, unsigned short* __restrict__ oGh, unsigned short* __restrict__ oGl)
{
    const int st = blockIdx.z;
    const int tkt = blockIdx.x, b = blockIdx.y, d = threadIdx.x;
    const int ntok = st ? LG : LS;
    if (tkt >= ntok) return;
    const float* x = st ? xG : xS;
    const float* w = st ? wG : wS;
    const float* bias = st ? bG : bS;
    float* out = st ? oG : oS;
    unsigned short* oh = st ? oGh : oSh;
    unsigned short* ol = st ? oGl : oSl;
    const int in_dim = st ? 18 : 3647, tok_dim = st ? 2 : 64;

    __shared__ float xv[64];
    if (d < tok_dim) {
        int idx = tkt*tok_dim + d;
        xv[d] = (idx < in_dim) ? x[(size_t)b*in_dim + idx] : 0.f;
    }
    __syncthreads();
    float acc = bias[d];
    for (int k=0;k<tok_dim;k++) acc += xv[k]*w[(size_t)k*DM + d];
    const size_t o = (size_t)(b*ntok + tkt)*DM + d;
    out[o] = acc;
    const unsigned short h = f2bh(acc);
    oh[o] = h;
    ol[o] = f2bh(acc - bh2f(h));
}

// ---------------- weight conversion -> GEMM-native tiled bf16 hi/lo ----------------
// v2: 4 n-tiles per block -> 1KB contiguous row reads (better HBM bursts).
// blocks [0,1600):    Win  (20 planes x 8 ktp x 10 ntg)
// blocks [1600,2240): Wout (20 planes x 16 ktp x 2 ntg)
// blocks [2240,3264): attention tiled copy (8 planes x 128 tiles)
__global__ __launch_bounds__(256) void convert_weights(
    const float* __restrict__ winS, const float* __restrict__ winG,
    const float* __restrict__ woutS, const float* __restrict__ woutG,
    const float* __restrict__ cai, const float* __restrict__ cao,
    const float* __restrict__ cgi, const float* __restrict__ cgo,
    unsigned short* __restrict__ winh, unsigned short* __restrict__ winl,
    unsigned short* __restrict__ wouth, unsigned short* __restrict__ woutl,
    unsigned short* __restrict__ atth, unsigned short* __restrict__ attl)
{
    const int tid = threadIdx.x;
    const int bid = blockIdx.x;

    if (bid >= 2240){
        // ---- attention tiled copy (no transpose; src f32 [512][512]) ----
        int e = bid - 2240;
        const int job = e >> 7, rem = e & 127;
        const int kt2 = rem >> 3, nt2 = rem & 7;
        const float* src =
            (job==3) ? cao : (job==7) ? cgo :
            (job< 3) ? cai + (size_t)job*512*512 : cgi + (size_t)(job-4)*512*512;
        const size_t tile = (size_t)job*ATT_PLANE + ((size_t)kt2*NT_ATT + nt2)*2048;
        const int n = tid >> 2, k8 = (tid & 3)*8;
        const float* sp = src + (size_t)(nt2*64 + n)*512 + kt2*32 + k8;
        const f32x4 v0 = __builtin_nontemporal_load((const f32x4*)sp);
        const f32x4 v1 = __builtin_nontemporal_load((const f32x4*)(sp+4));
        const float f[8] = {v0[0],v0[1],v0[2],v0[3],v1[0],v1[1],v1[2],v1[3]};
        short8 h8, l8;
        #pragma unroll
        for (int q=0;q<8;q++){
            const unsigned short h = f2bh(f[q]);
            h8[q] = (short)h;
            l8[q] = (short)f2bh(f[q] - bh2f(h));
        }
        __builtin_nontemporal_store(h8, (short8*)(atth + tile + tid*8));
        __builtin_nontemporal_store(l8, (short8*)(attl + tile + tid*8));
        return;
    }

    // ---- transpose path: stage 64 rows x 256 cols, emit up to 4 n-tiles x 2 kt2 ----
    const float* src; unsigned short *dh, *dl; int K, N, NT, ntg, ktp;
    if (bid < 1600){
        const int plane = bid / 80, rem = bid % 80;
        const int s = plane & 1, layer = plane >> 1;
        src = (s ? winG : winS) + (size_t)layer*DM*DPROJ;
        dh = winh + (size_t)plane*WIN_PLANE;
        dl = winl + (size_t)plane*WIN_PLANE;
        K = DM; N = DPROJ; NT = NT_IN;
        ktp = rem / 10; ntg = rem % 10;     // ktp in [0,8), ntg in [0,10)
    } else {
        const int i = bid - 1600;
        const int plane = i / 32, rem = i % 32;
        const int s = plane & 1, layer = plane >> 1;
        src = (s ? woutG : woutS) + (size_t)layer*DIN*DM;
        dh = wouth + (size_t)plane*WOUT_PLANE;
        dl = woutl + (size_t)plane*WOUT_PLANE;
        K = DIN; N = DM; NT = NT_OUT;
        ktp = rem / 2; ntg = rem % 2;       // ktp in [0,16), ntg in [0,2)
    }

    __shared__ float tile[64][268];
    #pragma unroll
    for (int i=0;i<16;i++){
        const int kk = (tid>>6) + i*4;
        const int c4 = (tid&63)*4;
        const int n = ntg*256 + c4;
        f32x4 v = {0.f,0.f,0.f,0.f};
        const float* sp = src + (size_t)(ktp*64+kk)*N + n;
        if (n + 3 < N) v = __builtin_nontemporal_load((const f32x4*)sp);
        else {
            if (n   < N) v[0] = sp[0];
            if (n+1 < N) v[1] = sp[1];
            if (n+2 < N) v[2] = sp[2];
            if (n+3 < N) v[3] = sp[3];
        }
        tile[kk][c4]=v[0]; tile[kk][c4+1]=v[1]; tile[kk][c4+2]=v[2]; tile[kk][c4+3]=v[3];
    }
    __syncthreads();

    const int n_l = tid >> 2, k8 = (tid & 3)*8;
    #pragma unroll
    for (int ts=0; ts<4; ++ts){
        const int nt = ntg*4 + ts;
        if (nt >= NT) break;
        #pragma unroll
        for (int i=0;i<2;i++){
            const int kt2 = ktp*2 + i;
            short8 h8, l8;
            #pragma unroll
            for (int q=0;q<8;q++){
                const float f = tile[i*32 + k8 + q][ts*64 + n_l];
                const unsigned short h = f2bh(f);
                h8[q] = (short)h;
                l8[q] = (short)f2bh(f - bh2f(h));
            }
            const size_t off = ((size_t)kt2*NT + nt)*2048 + tid*8;
            __builtin_nontemporal_store(h8, (short8*)(dh + off));
            __builtin_nontemporal_store(l8, (short8*)(dl + off));
        }
    }
}

// ---------------- split-K MFMA GEMM, pre-split bf16; W in tiled layout ----------------
struct GemmJob {
    const unsigned short* Ah; const unsigned short* Al;   // activations [M][K]
    const unsigned short* Wh; const unsigned short* Wl;   // tiled planes
    float* part; int M;
};

template<int NSPLIT>
__global__ __launch_bounds__(256) void gemm_mfma(GemmJob j0, GemmJob j1, GemmJob j2,
                                                 int N, int K, int NT)
{
    const int z = blockIdx.z;
    const int job = z / NSPLIT, split = z % NSPLIT;
    GemmJob jb = (job==0) ? j0 : (job==1 ? j1 : j2);
    const int bm = blockIdx.y*64, bn64 = blockIdx.x;
    const int M = jb.M;
    if (bm >= M) return;

    constexpr int SR = 40;
    __shared__ unsigned short AhS[2][64*SR], AlS[2][64*SR];
    __shared__ unsigned short BhS[2][64*SR], BlS[2][64*SR];

    const int tid = threadIdx.x;
    const int r0 = tid >> 2, k0off = (tid & 3)*8;
    const bool aok = (bm + r0 < M);
    const unsigned short* Aph = jb.Ah + (size_t)(bm+r0)*K;
    const unsigned short* Apl = jb.Al + (size_t)(bm+r0)*K;

    const int Kper = K / NSPLIT;
    const int koff = split * Kper;
    const int nk = Kper / 32;

    const size_t wbase = ((size_t)(koff >> 5)*NT + bn64)*2048 + (size_t)tid*8;
    const size_t wstep = (size_t)NT*2048;

    const short8 z8 = {0,0,0,0,0,0,0,0};
    short8 ra_h = z8, ra_l = z8, rw_h = z8, rw_l = z8;

    auto loadT = [&](int k0, int tstep){
        if (aok){
            ra_h = *(const short8*)(Aph + k0 + k0off);
            ra_l = *(const short8*)(Apl + k0 + k0off);
        } else { ra_h = z8; ra_l = z8; }
        rw_h = *(const short8*)(jb.Wh + wbase + (size_t)tstep*wstep);
        rw_l = *(const short8*)(jb.Wl + wbase + (size_t)tstep*wstep);
    };
    auto storeT = [&](int buf){
        *(short8*)&AhS[buf][r0*SR + k0off] = ra_h;
        *(short8*)&AlS[buf][r0*SR + k0off] = ra_l;
        *(short8*)&BhS[buf][r0*SR + k0off] = rw_h;
        *(short8*)&BlS[buf][r0*SR + k0off] = rw_l;
    };

    const int l = tid & 63, w = tid >> 6;
    const int fr = l & 15, kg = (l >> 4)*8;

    f32x4 acc0 = {0.f,0.f,0.f,0.f};
    f32x4 acc1 = {0.f,0.f,0.f,0.f};
    f32x4 acc2 = {0.f,0.f,0.f,0.f};
    f32x4 acc3 = {0.f,0.f,0.f,0.f};

    loadT(koff, 0);
    storeT(0);
    __syncthreads();
    for (int t=0; t<nk; ++t){
        const int cur = t & 1;
        if (t+1 < nk) loadT(koff + (t+1)*32, t+1);

        const short8 ah = *(const short8*)&AhS[cur][(w*16+fr)*SR + kg];
        const short8 al = *(const short8*)&AlS[cur][(w*16+fr)*SR + kg];
        {
            const short8 bh = *(const short8*)&BhS[cur][(fr)*SR + kg];
            const short8 bl = *(const short8*)&BlS[cur][(fr)*SR + kg];
            acc0 = __builtin_amdgcn_mfma_f32_16x16x32_bf16(ah, bh, acc0, 0,0,0);
            acc0 = __builtin_amdgcn_mfma_f32_16x16x32_bf16(ah, bl, acc0, 0,0,0);
            acc0 = __builtin_amdgcn_mfma_f32_16x16x32_bf16(al, bh, acc0, 0,0,0);
        }
        {
            const short8 bh = *(const short8*)&BhS[cur][(16+fr)*SR + kg];
            const short8 bl = *(const short8*)&BlS[cur][(16+fr)*SR + kg];
            acc1 = __builtin_amdgcn_mfma_f32_16x16x32_bf16(ah, bh, acc1, 0,0,0);
            acc1 = __builtin_amdgcn_mfma_f32_16x16x32_bf16(ah, bl, acc1, 0,0,0);
            acc1 = __builtin_amdgcn_mfma_f32_16x16x32_bf16(al, bh, acc1, 0,0,0);
        }
        {
            const short8 bh = *(const short8*)&BhS[cur][(32+fr)*SR + kg];
            const short8 bl = *(const short8*)&BlS[cur][(32+fr)*SR + kg];
            acc2 = __builtin_amdgcn_mfma_f32_16x16x32_bf16(ah, bh, acc2, 0,0,0);
            acc2 = __builtin_amdgcn_mfma_f32_16x16x32_bf16(ah, bl, acc2, 0,0,0);
            acc2 = __builtin_amdgcn_mfma_f32_16x16x32_bf16(al, bh, acc2, 0,0,0);
        }
        {
            const short8 bh = *(const short8*)&BhS[cur][(48+fr)*SR + kg];
            const short8 bl = *(const short8*)&BlS[cur][(48+fr)*SR + kg];
            acc3 = __builtin_amdgcn_mfma_f32_16x16x32_bf16(ah, bh, acc3, 0,0,0);
            acc3 = __builtin_amdgcn_mfma_f32_16x16x32_bf16(ah, bl, acc3, 0,0,0);
            acc3 = __builtin_amdgcn_mfma_f32_16x16x32_bf16(al, bh, acc3, 0,0,0);
        }
        if (t+1 < nk) storeT(cur^1);
        __syncthreads();
    }

    // C/D layout (m89-verified): col = lane&15, row = (lane>>4)*4 + reg
    float* __restrict__ P = jb.part + (size_t)split*M*N;
    const int rbase = bm + w*16 + (l>>4)*4;
    const int bn = bn64*64;
    #pragma unroll
    for (int nt=0; nt<4; ++nt){
        const f32x4 a = (nt==0)?acc0 : (nt==1)?acc1 : (nt==2)?acc2 : acc3;
        const int n = bn + nt*16 + fr;
        if (n < N){
            #pragma unroll
            for (int j=0;j<4;j++){
                const int m = rbase + j;
                if (m < M) P[(size_t)m*N + n] = a[j];
            }
        }
    }
}

// ---------------- reduce partials (+bias, +res, +optional bf16 planes) ----------------
struct RJob { const float* part; const float* bias; const float* res; float* C;
              unsigned short* ph; unsigned short* pl; int M; };

template<int NS>
__global__ __launch_bounds__(256) void reduce_k(RJob j0, RJob j1, int N)
{
    RJob j = blockIdx.y ? j1 : j0;
    const size_t total = (size_t)j.M*N;
    const size_t i4 = ((size_t)blockIdx.x*256 + threadIdx.x)*4;
    if (i4 >= total) return;
    float4 s = *(const float4*)(j.part + i4);
    #pragma unroll
    for (int t=1;t<NS;t++){
        const float4 v = *(const float4*)(j.part + (size_t)t*total + i4);
        s.x+=v.x; s.y+=v.y; s.z+=v.z; s.w+=v.w;
    }
    const int n = (int)(i4 % (size_t)N);
    if (j.bias){ s.x+=j.bias[n]; s.y+=j.bias[n+1]; s.z+=j.bias[n+2]; s.w+=j.bias[n+3]; }
    if (j.res){ const float4 r = *(const float4*)(j.res + i4); s.x+=r.x; s.y+=r.y; s.z+=r.z; s.w+=r.w; }
    if (j.C) *(float4*)(j.C + i4) = s;
    if (j.ph){
        const float f[4] = {s.x, s.y, s.z, s.w};
        short4_ h4, l4;
        #pragma unroll
        for (int q=0;q<4;q++){
            const unsigned short h = f2bh(f[q]);
            h4[q] = (short)h;
            l4[q] = (short)f2bh(f[q] - bh2f(h));
        }
        *(short4_*)(j.ph + i4) = h4;
        *(short4_*)(j.pl + i4) = l4;
    }
}

// ---------------- mamba prep: reduce 2 partials + conv + silu + softplus ----------------
struct PrepJob {
    const float* part;     // [SP_IN][R][DPROJ]
    float* xh; float* Bc; float* Cc; float* dtw;
    const float* cw; const float* cb; const float* dtb;
    int R, L;
};

__device__ __forceinline__ float4 psum2(const float* p, size_t pstr){
    float4 a = *(const float4*)p;
    const float4 b = *(const float4*)(p + pstr);
    a.x += b.x; a.y += b.y; a.z += b.z; a.w += b.w;
    return a;
}

__global__ __launch_bounds__(256) void mamba_prep(PrepJob js, PrepJob jg)
{
    PrepJob j = blockIdx.y ? jg : js;
    const int R = j.R, L = j.L;
    constexpr int QPR = 324;   // 320 (conv) + 4 (dt) quads per row
    const int q = blockIdx.x*256 + threadIdx.x;
    if (q >= R*QPR) return;
    const int r = q / QPR, qi = q % QPR;
    const int l = r % L;
    const size_t pstr = (size_t)R*DPROJ;
    const float* base = j.part + (size_t)r*DPROJ;

    if (qi < 320) {                 // ---- conv region
        const int cc = qi*4;        // 0..1276
        float tk[4][4];
        #pragma unroll
        for (int k=0;k<4;k++){
            const int lr = l - 3 + k;
            if (lr >= 0){
                float4 v = psum2(j.part + (size_t)(r-3+k)*DPROJ + 1024 + cc, pstr);
                tk[k][0]=v.x; tk[k][1]=v.y; tk[k][2]=v.z; tk[k][3]=v.w;
            } else {
                tk[k][0]=0.f; tk[k][1]=0.f; tk[k][2]=0.f; tk[k][3]=0.f;
            }
        }
        const float4 cb4 = *(const float4*)(j.cb + cc);
        const float cba[4] = {cb4.x, cb4.y, cb4.z, cb4.w};
        float out[4];
        #pragma unroll
        for (int jj=0;jj<4;jj++){
            const float4 wv = *(const float4*)(j.cw + (size_t)(cc+jj)*4);
            float v = cba[jj] + wv.x*tk[0][jj] + wv.y*tk[1][jj]
                              + wv.z*tk[2][jj] + wv.w*tk[3][jj];
            out[jj] = siluf(v);
        }
        float4 o4; o4.x=out[0]; o4.y=out[1]; o4.z=out[2]; o4.w=out[3];
        if (cc < 1024)       *(float4*)(j.xh + (size_t)r*1024 + cc)        = o4;
        else if (cc < 1152)  *(float4*)(j.Bc + (size_t)r*128 + (cc-1024))  = o4;
        else                 *(float4*)(j.Cc + (size_t)r*128 + (cc-1152))  = o4;
    } else {                        // ---- dt region
        const int hd = (qi-320)*4;  // 0,4,8,12
        float4 s = psum2(base + 2304 + hd, pstr);
        const float4 b4 = *(const float4*)(j.dtb + hd);
        float raw[4] = {s.x+b4.x, s.y+b4.y, s.z+b4.z, s.w+b4.w};
        float4 o4;
        float* op = &o4.x;
        #pragma unroll
        for (int jj=0;jj<4;jj++)
            op[jj] = (raw[jj] > 20.f) ? raw[jj] : log1pf(expf(raw[jj]));
        *(float4*)(j.dtw + (size_t)r*16 + hd) = o4;
    }
}

// ---------------- fused: G = decay .* (C @ B^T); Y = G @ X + D*X per (head,batch,stack) ----------------
__global__ __launch_bounds__(256) void mamba_y(
    const float* __restrict__ Bc_s, const float* __restrict__ Cc_s,
    const float* __restrict__ xh_s, const float* __restrict__ dtw_s,
    const float* __restrict__ al_s, const float* __restrict__ Dw_s, float* __restrict__ y_s,
    const float* __restrict__ Bc_g, const float* __restrict__ Cc_g,
    const float* __restrict__ xh_g, const float* __restrict__ dtw_g,
    const float* __restrict__ al_g, const float* __restrict__ Dw_g, float* __restrict__ y_g)
{
    const int h = blockIdx.x, b = blockIdx.y, st = blockIdx.z;
    const float* Bc  = st ? Bc_g  : Bc_s;
    const float* Cc  = st ? Cc_g  : Cc_s;
    const float* xh  = st ? xh_g  : xh_s;
    const float* dtw = st ? dtw_g : dtw_s;
    const float* al  = st ? al_g  : al_s;
    const float* Dw  = st ? Dw_g  : Dw_s;
    float* y = st ? y_g : y_s;
    const int L = st ? LG : LS;

    const int t = threadIdx.x;
    constexpr int SB = 132, SG = 60, SX = 68;
    __shared__ float Bm[64*SB], Cm[64*SB];
    __shared__ float Gm[64*SG], Xm[64*SX];
    __shared__ float dts[64], sps[64];

    const float Ah = -expf(al[h]);
    const float Dh = Dw[h];

    // dt + prefix scan (wave 0)
    if (t < 64){
        float dtv = (t < L) ? dtw[(size_t)(b*L+t)*16 + h] : 0.f;
        float s = dtv;
        #pragma unroll
        for (int d=1; d<64; d<<=1){
            float o = __shfl_up(s, d, 64);
            if (t >= d) s += o;
        }
        dts[t] = dtv; sps[t] = s;
    }
    // stage B, C, X tiles
    for (int idx = t; idx < L*32; idx += 256){
        const int l = idx >> 5, c4 = (idx & 31)*4;
        *(float4*)&Bm[l*SB + c4] = *(const float4*)(Bc + (size_t)(b*L+l)*128 + c4);
        *(float4*)&Cm[l*SB + c4] = *(const float4*)(Cc + (size_t)(b*L+l)*128 + c4);
    }
    for (int idx = t; idx < L*16; idx += 256){
        const int l = idx >> 4, c4 = (idx & 15)*4;
        *(float4*)&Xm[l*SX + c4] = *(const float4*)(xh + (size_t)(b*L+l)*1024 + h*64 + c4);
    }
    __syncthreads();

    const int ti = t >> 4, tj = t & 15;

    // G = decay .* (C @ B^T), computed in-block
    {
        float acc[4][4] = {};
        for (int k0=0;k0<128;k0+=4){
            float4 cr[4], br[4];
            #pragma unroll
            for (int a=0;a<4;a++) cr[a] = *(const float4*)&Cm[(ti+16*a)*SB + k0];
            #pragma unroll
            for (int qq=0;qq<4;qq++) br[qq] = *(const float4*)&Bm[(tj+16*qq)*SB + k0];
            #pragma unroll
            for (int a=0;a<4;a++)
                #pragma unroll
                for (int qq=0;qq<4;qq++)
                    acc[a][qq] += cr[a].x*br[qq].x + cr[a].y*br[qq].y
                                + cr[a].z*br[qq].z + cr[a].w*br[qq].w;
        }
        #pragma unroll
        for (int a=0;a<4;a++){
            const int i = ti + 16*a;
            if (i < L){
                const float si = sps[i];
                #pragma unroll
                for (int qq=0;qq<4;qq++){
                    const int jj = tj + 16*qq;
                    if (jj < L){
                        float gg = 0.f;
                        if (jj <= i)
                            gg = expf(Ah*(si - sps[jj])) * dts[jj] * acc[a][qq];
                        Gm[i*SG + jj] = gg;
                    }
                }
            }
        }
    }
    __syncthreads();

    // Y = G @ X + D*X
    int la[4];
    #pragma unroll
    for (int a=0;a<4;a++) la[a] = ti + 16*a;
    float accY[4][4] = {};
    for (int m=0; m<L; ++m){
        float xr[4], gr[4];
        #pragma unroll
        for (int qq=0;qq<4;qq++) xr[qq] = Xm[m*SX + tj + 16*qq];
        #pragma unroll
        for (int a=0;a<4;a++) gr[a] = (la[a] < L) ? Gm[la[a]*SG + m] : 0.f;
        #pragma unroll
        for (int a=0;a<4;a++)
            #pragma unroll
            for (int qq=0;qq<4;qq++) accY[a][qq] = fmaf(gr[a], xr[qq], accY[a][qq]);
    }
    #pragma unroll
    for (int a=0;a<4;a++){
        if (la[a] < L){
            float* yrow = y + (size_t)(b*L + la[a])*DIN + h*HD;
            #pragma unroll
            for (int qq=0;qq<4;qq++){
                const int col = tj + 16*qq;
                yrow[col] = accY[a][qq] + Dh * Xm[la[a]*SX + col];
            }
        }
    }
}

// ---------------- gated RMSNorm: silu(z) from in-proj partials, -> bf16 planes ----------------
__global__ __launch_bounds__(256) void gated_rmsnorm(
    const float* __restrict__ y_s, const float* __restrict__ part_s, const float* __restrict__ nw_s,
    unsigned short* __restrict__ oh_s, unsigned short* __restrict__ ol_s,
    const float* __restrict__ y_g, const float* __restrict__ part_g, const float* __restrict__ nw_g,
    unsigned short* __restrict__ oh_g, unsigned short* __restrict__ ol_g)
{
    int r = blockIdx.x, t = threadIdx.x;
    int st = (r >= RS);
    int row = st ? r - RS : r;
    const float* y  = (st ? y_g  : y_s) + (size_t)row*DIN;
    const float* zp = (st ? part_g : part_s) + (size_t)row*DPROJ;
    const size_t pstr = (size_t)(st ? RG : RS)*DPROJ;
    const float* nw = st ? nw_g : nw_s;
    unsigned short* oh = (st ? oh_g : oh_s) + (size_t)row*DIN;
    unsigned short* ol = (st ? ol_g : ol_s) + (size_t)row*DIN;

    float g[4]; float s2 = 0.f;
    #pragma unroll
    for (int i=0;i<4;i++){
        int idx = t + i*256;
        const float zv = zp[idx] + zp[pstr + idx];
        float gv = y[idx] * siluf(zv);
        g[i] = gv; s2 += gv*gv;
    }
    #pragma unroll
    for (int o2=32;o2;o2>>=1) s2 += __shfl_xor(s2, o2, 64);
    __shared__ float red[4];
    if ((t & 63) == 0) red[t>>6] = s2;
    __syncthreads();
    float S2 = red[0]+red[1]+red[2]+red[3];
    float scale = rsqrtf(S2*(1.f/DIN) + 1e-5f);
    #pragma unroll
    for (int i=0;i<4;i++){
        int idx = t + i*256;
        const float val = g[i]*scale*nw[idx];
        const unsigned short h = f2bh(val);
        oh[idx] = h;
        ol[idx] = f2bh(val - bh2f(h));
    }
}

// ---------------- LayerNorm rows -> bf16 planes ----------------
__global__ __launch_bounds__(256) void ln_rows(
    const float* __restrict__ x, const float* __restrict__ w, const float* __restrict__ b,
    unsigned short* __restrict__ outh, unsigned short* __restrict__ outl, int D)
{
    int r = blockIdx.x, t = threadIdx.x;
    const float* xr = x + (size_t)r*D;
    float s = 0.f, s2 = 0.f;
    for (int i=t;i<D;i+=256){ float v = xr[i]; s += v; s2 += v*v; }
    #pragma unroll
    for (int o=32;o;o>>=1){ s += __shfl_xor(s,o,64); s2 += __shfl_xor(s2,o,64); }
    __shared__ float red[8];
    if ((t & 63) == 0){ red[t>>6] = s; red[4+(t>>6)] = s2; }
    __syncthreads();
    float S  = red[0]+red[1]+red[2]+red[3];
    float S2 = red[4]+red[5]+red[6]+red[7];
    float mean = S/D;
    float var  = S2/D - mean*mean;
    float inv  = rsqrtf(var + 1e-5f);
    for (int i=t;i<D;i+=256){
        const float val = (xr[i]-mean)*inv*w[i] + b[i];
        const unsigned short h = f2bh(val);
        outh[(size_t)r*D + i] = h;
        outl[(size_t)r*D + i] = f2bh(val - bh2f(h));
    }
}

// ---------------- cross-attention core: split-K partials + bias in, bf16 planes out ----------------
template<int LQ, int LKV, int NS>
__global__ __launch_bounds__(256) void mha_attn2(
    const float* __restrict__ pq, const float* __restrict__ pk, const float* __restrict__ pv,
    const float* __restrict__ qb, const float* __restrict__ kb, const float* __restrict__ vb,
    int Mq, int Mkv,
    unsigned short* __restrict__ outh, unsigned short* __restrict__ outl)
{
    const int hh = blockIdx.x, b = blockIdx.y, t = threadIdx.x;
    const size_t strQ = (size_t)Mq*DM, strKV = (size_t)Mkv*DM;
    constexpr int SD = 68;
    constexpr int SS = 60;
    constexpr int QT = (LQ +15)/16;
    constexpr int KT = (LKV+15)/16;
    __shared__ float Qs[LQ*SD];
    __shared__ float Ks[LKV*SD];
    __shared__ float Vs[LKV*SD];
    __shared__ float Ps[LQ*SS];

    for (int idx = t; idx < LQ*16; idx += 256){
        const int r = idx>>4, c4 = (idx&15)*4;
        float4 v = *(const float4*)(qb + hh*64 + c4);
        const size_t off = (size_t)(b*LQ+r)*DM + hh*64 + c4;
        #pragma unroll
        for (int s=0;s<NS;s++){
            const float4 u = *(const float4*)(pq + s*strQ + off);
            v.x+=u.x; v.y+=u.y; v.z+=u.z; v.w+=u.w;
        }
        *(float4*)&Qs[r*SD+c4] = v;
    }
    for (int idx = t; idx < LKV*16; idx += 256){
        const int r = idx>>4, c4 = (idx&15)*4;
        float4 kv = *(const float4*)(kb + hh*64 + c4);
        float4 vv = *(const float4*)(vb + hh*64 + c4);
        const size_t off = (size_t)(b*LKV+r)*DM + hh*64 + c4;
        #pragma unroll
        for (int s=0;s<NS;s++){
            const float4 ku = *(const float4*)(pk + s*strKV + off);
            const float4 vu = *(const float4*)(pv + s*strKV + off);
            kv.x+=ku.x; kv.y+=ku.y; kv.z+=ku.z; kv.w+=ku.w;
            vv.x+=vu.x; vv.y+=vu.y; vv.z+=vu.z; vv.w+=vu.w;
        }
        *(float4*)&Ks[r*SD+c4] = kv;
        *(float4*)&Vs[r*SD+c4] = vv;
    }
    __syncthreads();

    const int ti = t>>4, tj = t&15;

    {
        float acc[QT][KT];
        #pragma unroll
        for (int a=0;a<QT;a++)
            #pragma unroll
            for (int q=0;q<KT;q++) acc[a][q] = 0.f;
        for (int k0=0;k0<64;k0+=4){
            float4 qr[QT], kr[KT];
            #pragma unroll
            for (int a=0;a<QT;a++){
                int rr = ti+16*a; if (rr >= LQ) rr = LQ-1;
                qr[a] = *(const float4*)&Qs[rr*SD+k0];
            }
            #pragma unroll
            for (int q=0;q<KT;q++){
                int rr = tj+16*q; if (rr >= LKV) rr = LKV-1;
                kr[q] = *(const float4*)&Ks[rr*SD+k0];
            }
            #pragma unroll
            for (int a=0;a<QT;a++)
                #pragma unroll
                for (int q=0;q<KT;q++)
                    acc[a][q] += qr[a].x*kr[q].x + qr[a].y*kr[q].y
                               + qr[a].z*kr[q].z + qr[a].w*kr[q].w;
        }
        #pragma unroll
        for (int a=0;a<QT;a++){
            const int i = ti+16*a;
            if (i < LQ){
                #pragma unroll
                for (int q=0;q<KT;q++){
                    const int jj = tj+16*q;
                    if (jj < LKV) Ps[i*SS+jj] = acc[a][q]*0.125f;
                }
            }
        }
    }
    __syncthreads();

    if (t < LQ){
        float mx = -1e30f;
        for (int j=0;j<LKV;j++) mx = fmaxf(mx, Ps[t*SS+j]);
        float se = 0.f;
        for (int j=0;j<LKV;j++){ float e = expf(Ps[t*SS+j]-mx); Ps[t*SS+j] = e; se += e; }
        const float inv = 1.f/se;
        for (int j=0;j<LKV;j++) Ps[t*SS+j] *= inv;
    }
    __syncthreads();

    {
        float o[QT][4];
        #pragma unroll
        for (int a=0;a<QT;a++){ o[a][0]=0.f; o[a][1]=0.f; o[a][2]=0.f; o[a][3]=0.f; }
        for (int m=0;m<LKV;m++){
            const float4 vv = *(const float4*)&Vs[m*SD + tj*4];
            #pragma unroll
            for (int a=0;a<QT;a++){
                const int rr = ti+16*a;
                const float pv2 = (rr < LQ) ? Ps[rr*SS+m] : 0.f;
                o[a][0] = fmaf(pv2, vv.x, o[a][0]);
                o[a][1] = fmaf(pv2, vv.y, o[a][1]);
                o[a][2] = fmaf(pv2, vv.z, o[a][2]);
                o[a][3] = fmaf(pv2, vv.w, o[a][3]);
            }
        }
        #pragma unroll
        for (int a=0;a<QT;a++){
            const int rr = ti+16*a;
            if (rr < LQ){
                short4_ h4, l4;
                #pragma unroll
                for (int q=0;q<4;q++){
                    const unsigned short h = f2bh(o[a][q]);
                    h4[q] = (short)h;
                    l4[q] = (short)f2bh(o[a][q] - bh2f(h));
                }
                const size_t off = (size_t)(b*LQ+rr)*DM + hh*64 + tj*4;
                *(short4_*)(outh + off) = h4;
                *(short4_*)(outl + off) = l4;
            }
        }
    }
}

// ---------------- fused head: meanpool + LN + classifier ----------------
__global__ __launch_bounds__(512) void head_fused(
    const float* __restrict__ xs, const float* __restrict__ xg,
    const float* __restrict__ lw, const float* __restrict__ lb,
    const float* __restrict__ cw, const float* __restrict__ cb,
    float* __restrict__ out)
{
    const int b = blockIdx.x, t = threadIdx.x;
    __shared__ float fr[1024];
    __shared__ float red[16];
    __shared__ float pr[55*8];
    {
        float s = 0.f;
        for (int l=0;l<LS;l++) s += xs[(size_t)(b*LS+l)*DM + t];
        fr[t] = s*(1.f/LS);
        float g = 0.f;
        for (int l=0;l<LG;l++) g += xg[(size_t)(b*LG+l)*DM + t];
        fr[512+t] = g*(1.f/LG);
    }
    __syncthreads();
    float v0 = fr[t], v1 = fr[512+t];
    float sm = v0+v1, sq = v0*v0 + v1*v1;
    #pragma unroll
    for (int o=32;o;o>>=1){ sm += __shfl_xor(sm,o,64); sq += __shfl_xor(sq,o,64); }
    if ((t&63)==0){ red[t>>6] = sm; red[8+(t>>6)] = sq; }
    __syncthreads();
    float S=0.f, Q=0.f;
    #pragma unroll
    for (int i=0;i<8;i++){ S += red[i]; Q += red[8+i]; }
    const float mean = S*(1.f/1024.f);
    const float var  = Q*(1.f/1024.f) - mean*mean;
    const float inv  = rsqrtf(var + 1e-5f);
    fr[t]     = (v0-mean)*inv*lw[t]     + lb[t];
    fr[512+t] = (v1-mean)*inv*lw[512+t] + lb[512+t];
    __syncthreads();
    {
        const int c = t & 63, pp = t >> 6;
        if (c < 55){
            float a = 0.f;
            const float* wr = cw + (size_t)c*1024 + pp*128;
            const float* xr = fr + pp*128;
            #pragma unroll 4
            for (int k=0;k<128;k++) a = fmaf(xr[k], wr[k], a);
            pr[c*8+pp] = a;
        }
    }
    __syncthreads();
    if (t < 55){
        float a = cb[t];
        #pragma unroll
        for (int p2=0;p2<8;p2++) a += pr[t*8+p2];
        out[b*55 + t] = a;
    }
}

// ---------------- launch ----------------
extern "C" void kernel_launch(void* const* d_in, const int* in_sizes, int n_in,
                              void* d_out, int out_size, void* d_ws, size_t ws_size,
                              hipStream_t stream)
{
    (void)in_sizes; (void)n_in; (void)out_size; (void)ws_size;
    const float* x_spectra = (const float*)d_in[0];
    const float* x_gaia    = (const float*)d_in[1];
    const float* tok_w_s   = (const float*)d_in[2];
    const float* tok_b_s   = (const float*)d_in[3];
    const float* tok_w_g   = (const float*)d_in[4];
    const float* tok_b_g   = (const float*)d_in[5];
    const float* ms_Win    = (const float*)d_in[6];
    const float* ms_conv_w = (const float*)d_in[7];
    const float* ms_conv_b = (const float*)d_in[8];
    const float* ms_dtb    = (const float*)d_in[9];
    const float* ms_Alog   = (const float*)d_in[10];
    const float* ms_D      = (const float*)d_in[11];
    const float* ms_nw     = (const float*)d_in[12];
    const float* ms_Wout   = (const float*)d_in[13];
    const float* mg_Win    = (const float*)d_in[14];
    const float* mg_conv_w = (const float*)d_in[15];
    const float* mg_conv_b = (const float*)d_in[16];
    const float* mg_dtb    = (const float*)d_in[17];
    const float* mg_Alog   = (const float*)d_in[18];
    const float* mg_D      = (const float*)d_in[19];
    const float* mg_nw     = (const float*)d_in[20];
    const float* mg_Wout   = (const float*)d_in[21];
    const float* cas_ln_w  = (const float*)d_in[22];
    const float* cas_ln_b  = (const float*)d_in[23];
    const float* cas_in_w  = (const float*)d_in[24];
    const float* cas_in_b  = (const float*)d_in[25];
    const float* cas_out_w = (const float*)d_in[26];
    const float* cas_out_b = (const float*)d_in[27];
    const float* cag_ln_w  = (const float*)d_in[28];
    const float* cag_ln_b  = (const float*)d_in[29];
    const float* cag_in_w  = (const float*)d_in[30];
    const float* cag_in_b  = (const float*)d_in[31];
    const float* cag_out_w = (const float*)d_in[32];
    const float* cag_out_b = (const float*)d_in[33];
    const float* cls_ln_w  = (const float*)d_in[34];
    const float* cls_ln_b  = (const float*)d_in[35];
    const float* cls_w     = (const float*)d_in[36];
    const float* cls_b     = (const float*)d_in[37];

    float* p = (float*)d_ws;
    auto alloc = [&](size_t n){ float* r = p; p += n; return r; };
    float* xs       = alloc((size_t)RS*DM);
    float* xg       = alloc((size_t)RG*DM);
    float* y_s      = alloc((size_t)RS*DIN);
    float* y_g      = alloc((size_t)RG*DIN);
    float* part_inS  = alloc((size_t)SP_IN*RS*DPROJ);
    float* part_inG  = alloc((size_t)SP_IN*RG*DPROJ);
    float* part_outS = alloc((size_t)SP_OUT*RS*DM);
    float* part_outG = alloc((size_t)SP_OUT*RG*DM);
    float* part_q    = alloc((size_t)SP_ATT*RS*DM);
    float* part_k    = alloc((size_t)SP_ATT*RS*DM);
    float* part_v    = alloc((size_t)SP_ATT*RS*DM);
    float* xh_s    = alloc((size_t)RS*1024);
    float* xh_g    = alloc((size_t)RG*1024);
    float* Bc_s    = alloc((size_t)RS*128);
    float* Bc_g    = alloc((size_t)RG*128);
    float* Cc_s    = alloc((size_t)RS*128);
    float* Cc_g    = alloc((size_t)RG*128);
    float* dtw_s   = alloc((size_t)RS*16);
    float* dtw_g   = alloc((size_t)RG*16);

    unsigned short* up = (unsigned short*)p;
    auto ualloc = [&](size_t n){ unsigned short* r = up; up += n; return r; };
    unsigned short* xsh   = ualloc((size_t)RS*DM);
    unsigned short* xsl   = ualloc((size_t)RS*DM);
    unsigned short* xgh   = ualloc((size_t)RG*DM);
    unsigned short* xgl   = ualloc((size_t)RG*DM);
    unsigned short* ynh_s = ualloc((size_t)RS*DIN);
    unsigned short* ynl_s = ualloc((size_t)RS*DIN);
    unsigned short* ynh_g = ualloc((size_t)RG*DIN);
    unsigned short* ynl_g = ualloc((size_t)RG*DIN);
    unsigned short* lnh   = ualloc((size_t)RS*DM);
    unsigned short* lnl   = ualloc((size_t)RS*DM);
    unsigned short* aoh   = ualloc((size_t)RS*DM);
    unsigned short* aol   = ualloc((size_t)RS*DM);
    unsigned short* atth  = ualloc((size_t)8*ATT_PLANE);
    unsigned short* attl  = ualloc((size_t)8*ATT_PLANE);
    unsigned short* winh  = ualloc((size_t)20*WIN_PLANE);
    unsigned short* winl  = ualloc((size_t)20*WIN_PLANE);
    unsigned short* wouth = ualloc((size_t)20*WOUT_PLANE);
    unsigned short* woutl = ualloc((size_t)20*WOUT_PLANE);

    // tiled attention plane bases: q,k,v,o for cas (0..3) and cag (4..7)
    unsigned short* casq_h = atth + 0*ATT_PLANE; unsigned short* casq_l = attl + 0*ATT_PLANE;
    unsigned short* cask_h = atth + 1*ATT_PLANE; unsigned short* cask_l = attl + 1*ATT_PLANE;
    unsigned short* casv_h = atth + 2*ATT_PLANE; unsigned short* casv_l = attl + 2*ATT_PLANE;
    unsigned short* caso_h = atth + 3*ATT_PLANE; unsigned short* caso_l = attl + 3*ATT_PLANE;
    unsigned short* cagq_h = atth + 4*ATT_PLANE; unsigned short* cagq_l = attl + 4*ATT_PLANE;
    unsigned short* cagk_h = atth + 5*ATT_PLANE; unsigned short* cagk_l = attl + 5*ATT_PLANE;
    unsigned short* cagv_h = atth + 6*ATT_PLANE; unsigned short* cagv_l = attl + 6*ATT_PLANE;
    unsigned short* cago_h = atth + 7*ATT_PLANE; unsigned short* cago_l = attl + 7*ATT_PLANE;

    // one-time weight conversion (tiled, NT loads/stores, 4 n-tiles/block)
    convert_weights<<<dim3(3264), 256, 0, stream>>>(
        ms_Win, mg_Win, ms_Wout, mg_Wout,
        cas_in_w, cas_out_w, cag_in_w, cag_out_w,
        winh, winl, wouth, woutl, atth, attl);

    // tokenize (both modalities)
    tokenize2<<<dim3(LS, BB, 2), 512, 0, stream>>>(
        x_spectra, tok_w_s, tok_b_s, xs, xsh, xsl,
        x_gaia,    tok_w_g, tok_b_g, xg, xgh, xgl);

    const int rblkS = (RS*DM + 1023)/1024;   // 228
    const int prepBlk = (RS*324 + 255)/256;  // 578

    // mamba stacks
    for (int i=0;i<NLAY;i++){
        const float* cw_s   = ms_conv_w + (size_t)i*1280*4;
        const float* cw_g   = mg_conv_w + (size_t)i*1280*4;
        const float* cbv_s  = ms_conv_b + (size_t)i*1280;
        const float* cbv_g  = mg_conv_b + (size_t)i*1280;
        const float* dtb_s  = ms_dtb  + (size_t)i*NH;
        const float* dtb_g  = mg_dtb  + (size_t)i*NH;
        const float* al_s   = ms_Alog + (size_t)i*NH;
        const float* al_g   = mg_Alog + (size_t)i*NH;
        const float* Dw_s   = ms_D    + (size_t)i*NH;
        const float* Dw_g   = mg_D    + (size_t)i*NH;
        const float* nw_s   = ms_nw   + (size_t)i*DIN;
        const float* nw_g   = mg_nw   + (size_t)i*DIN;

        const unsigned short* wih_s = winh + (size_t)(2*i+0)*WIN_PLANE;
        const unsigned short* wil_s = winl + (size_t)(2*i+0)*WIN_PLANE;
        const unsigned short* wih_g = winh + (size_t)(2*i+1)*WIN_PLANE;
        const unsigned short* wil_g = winl + (size_t)(2*i+1)*WIN_PLANE;
        const unsigned short* woh_s = wouth + (size_t)(2*i+0)*WOUT_PLANE;
        const unsigned short* wol_s = woutl + (size_t)(2*i+0)*WOUT_PLANE;
        const unsigned short* woh_g = wouth + (size_t)(2*i+1)*WOUT_PLANE;
        const unsigned short* wol_g = woutl + (size_t)(2*i+1)*WOUT_PLANE;

        GemmJob inS{xsh, xsl, wih_s, wil_s, part_inS, RS};
        GemmJob inG{xgh, xgl, wih_g, wil_g, part_inG, RG};
        gemm_mfma<SP_IN><<<dim3(NT_IN, 8, 2*SP_IN), 256, 0, stream>>>(
            inS, inG, inG, DPROJ, DM, NT_IN);

        PrepJob pjS{part_inS, xh_s, Bc_s, Cc_s, dtw_s, cw_s, cbv_s, dtb_s, RS, LS};
        PrepJob pjG{part_inG, xh_g, Bc_g, Cc_g, dtw_g, cw_g, cbv_g, dtb_g, RG, LG};
        mamba_prep<<<dim3(prepBlk, 2), 256, 0, stream>>>(pjS, pjG);

        mamba_y<<<dim3(NH, BB, 2), 256, 0, stream>>>(
            Bc_s, Cc_s, xh_s, dtw_s, al_s, Dw_s, y_s,
            Bc_g, Cc_g, xh_g, dtw_g, al_g, Dw_g, y_g);

        gated_rmsnorm<<<dim3(RS+RG), 256, 0, stream>>>(
            y_s, part_inS, nw_s, ynh_s, ynl_s,  y_g, part_inG, nw_g, ynh_g, ynl_g);

        GemmJob outS{ynh_s, ynl_s, woh_s, wol_s, part_outS, RS};
        GemmJob outG{ynh_g, ynl_g, woh_g, wol_g, part_outG, RG};
        gemm_mfma<SP_OUT><<<dim3(NT_OUT, 8, 2*SP_OUT), 256, 0, stream>>>(
            outS, outG, outG, DM, DIN, NT_OUT);

        RJob roS{part_outS, nullptr, nullptr, xs, xsh, xsl, RS};
        RJob roG{part_outG, nullptr, nullptr, xg, xgh, xgl, RG};
        reduce_k<SP_OUT><<<dim3(rblkS, 2), 256, 0, stream>>>(roS, roG, DM);
    }

    // cross-attention: xs = xs + MHA(LN(xs), xg)
    {
        ln_rows<<<dim3(RS), 256, 0, stream>>>(xs, cas_ln_w, cas_ln_b, lnh, lnl, DM);
        GemmJob jq{lnh, lnl, casq_h, casq_l, part_q, RS};
        GemmJob jk{xgh, xgl, cask_h, cask_l, part_k, RG};
        GemmJob jv{xgh, xgl, casv_h, casv_l, part_v, RG};
        gemm_mfma<SP_ATT><<<dim3(NT_ATT, 8, 3*SP_ATT), 256, 0, stream>>>(jq, jk, jv, DM, DM, NT_ATT);
        mha_attn2<LS,LG,SP_ATT><<<dim3(8,BB), 256, 0, stream>>>(
            part_q, part_k, part_v, cas_in_b, cas_in_b+512, cas_in_b+1024, RS, RG, aoh, aol);
        GemmJob jo{aoh, aol, caso_h, caso_l, part_outS, RS};
        gemm_mfma<SP_ATT><<<dim3(NT_ATT, 8, SP_ATT), 256, 0, stream>>>(jo, jo, jo, DM, DM, NT_ATT);
        RJob ro{part_outS, cas_out_b, xs, xs, xsh, xsl, RS};
        reduce_k<SP_ATT><<<dim3(rblkS, 1), 256, 0, stream>>>(ro, ro, DM);
    }

    // cross-attention: xg = xg + MHA(LN(xg), xs_updated)
    {
        ln_rows<<<dim3(RG), 256, 0, stream>>>(xg, cag_ln_w, cag_ln_b, lnh, lnl, DM);
        GemmJob jq{lnh, lnl, cagq_h, cagq_l, part_q, RG};
        GemmJob jk{xsh, xsl, cagk_h, cagk_l, part_k, RS};
        GemmJob jv{xsh, xsl, cagv_h, cagv_l, part_v, RS};
        gemm_mfma<SP_ATT><<<dim3(NT_ATT, 8, 3*SP_ATT), 256, 0, stream>>>(jq, jk, jv, DM, DM, NT_ATT);
        mha_attn2<LG,LS,SP_ATT><<<dim3(8,BB), 256, 0, stream>>>(
            part_q, part_k, part_v, cag_in_b, cag_in_b+512, cag_in_b+1024, RG, RS, aoh, aol);
        GemmJob jo{aoh, aol, cago_h, cago_l, part_outS, RG};
        gemm_mfma<SP_ATT><<<dim3(NT_ATT, 2, SP_ATT), 256, 0, stream>>>(jo, jo, jo, DM, DM, NT_ATT);
        RJob ro{part_outS, cag_out_b, xg, xg, nullptr, nullptr, RG};
        reduce_k<SP_ATT><<<dim3((RG*DM+1023)/1024, 1), 256, 0, stream>>>(ro, ro, DM);
    }

    // fused head
    head_fused<<<dim3(BB), 512, 0, stream>>>(xs, xg, cls_ln_w, cls_ln_b, cls_w, cls_b, (float*)d_out);
}

// Round 17
// 702.605 us; speedup vs baseline: 1.0204x; 1.0204x over previous
//
#include <hip/hip_runtime.h>
#include <cmath>

// ---------------- constants ----------------
constexpr int BB    = 8;     // batch
constexpr int LS    = 57;    // spectra tokens
constexpr int LG    = 9;     // gaia tokens
constexpr int RS    = BB*LS; // 456
constexpr int RG    = BB*LG; // 72
constexpr int DM    = 512;   // d_model
constexpr int DPROJ = 2320;
constexpr int DIN   = 1024;
constexpr int NH    = 16;    // mamba heads
constexpr int HD    = 64;    // mamba headdim
constexpr int NLAY  = 10;

constexpr int SP_IN  = 2;    // split-K for in-proj  (K=512  -> 256/split)
constexpr int SP_OUT = 4;    // split-K for out-proj (K=1024 -> 256/split)
constexpr int SP_ATT = 4;    // split-K for attention gemms (K=512 -> 128/split)

// tiled weight geometry: [kt2][nt2][64 n][32 k], 2048 shorts (4KB) per tile
constexpr int NT_IN  = 37;   // in-proj n-tiles (2320 -> padded 2368)
constexpr int NT_OUT = 8;    // out-proj n-tiles (512)
constexpr int NT_ATT = 8;    // attention n-tiles (512)
constexpr size_t WIN_PLANE  = (size_t)16*NT_IN*2048;   // K=512 -> 16 k-tiles
constexpr size_t WOUT_PLANE = (size_t)32*NT_OUT*2048;  // K=1024 -> 32 k-tiles
constexpr size_t ATT_PLANE  = (size_t)16*NT_ATT*2048;  // 512x512

__device__ __forceinline__ float siluf(float x){ return x / (1.f + expf(-x)); }

// ---------------- bf16 split helpers ----------------
typedef short  short8  __attribute__((ext_vector_type(8)));
typedef short  short4_ __attribute__((ext_vector_type(4)));
typedef float  f32x4   __attribute__((ext_vector_type(4)));

__device__ __forceinline__ unsigned short f2bh(float f){
    unsigned int u = __float_as_uint(f);
    u = u + 0x7FFFu + ((u >> 16) & 1u);
    return (unsigned short)(u >> 16);
}
__device__ __forceinline__ float bh2f(unsigned short h){
    return __uint_as_float(((unsigned int)h) << 16);
}

// ---------------- tokenize both modalities (+bf16 planes) ----------------
__global__ __launch_bounds__(512) void tokenize2(
    const float* __restrict__ xS, const float* __restrict__ wS, const float* __restrict__ bS,
    float* __restrict__ oS, unsigned short* __restrict__ oSh, unsigned short* __restrict__ oSl,
    const float* __restrict__ xG, const float* __restrict__ wG, const float* __restrict__ bG,
    float* __restrict__ oG, unsigned short* __restrict__ oGh, unsigned short* __restrict__ oGl)
{
    const int st = blockIdx.z;
    const int tkt = blockIdx.x, b = blockIdx.y, d = threadIdx.x;
    const int ntok = st ? LG : LS;
    if (tkt >= ntok) return;
    const float* x = st ? xG : xS;
    const float* w = st ? wG : wS;
    const float* bias = st ? bG : bS;
    float* out = st ? oG : oS;
    unsigned short* oh = st ? oGh : oSh;
    unsigned short* ol = st ? oGl : oSl;
    const int in_dim = st ? 18 : 3647, tok_dim = st ? 2 : 64;

    __shared__ float xv[64];
    if (d < tok_dim) {
        int idx = tkt*tok_dim + d;
        xv[d] = (idx < in_dim) ? x[(size_t)b*in_dim + idx] : 0.f;
    }
    __syncthreads();
    float acc = bias[d];
    for (int k=0;k<tok_dim;k++) acc += xv[k]*w[(size_t)k*DM + d];
    const size_t o = (size_t)(b*ntok + tkt)*DM + d;
    out[o] = acc;
    const unsigned short h = f2bh(acc);
    oh[o] = h;
    ol[o] = f2bh(acc - bh2f(h));
}

// ---------------- weight conversion -> GEMM-native tiled bf16 hi/lo ----------------
__global__ __launch_bounds__(256) void convert_weights(
    const float* __restrict__ winS, const float* __restrict__ winG,
    const float* __restrict__ woutS, const float* __restrict__ woutG,
    const float* __restrict__ cai, const float* __restrict__ cao,
    const float* __restrict__ cgi, const float* __restrict__ cgo,
    unsigned short* __restrict__ winh, unsigned short* __restrict__ winl,
    unsigned short* __restrict__ wouth, unsigned short* __restrict__ woutl,
    unsigned short* __restrict__ atth, unsigned short* __restrict__ attl)
{
    const int tid = threadIdx.x;
    const int bid = blockIdx.x;

    if (bid >= 8480){
        // ---- attention tiled copy (no transpose; src f32 [512][512]) ----
        int e = bid - 8480;
        const int job = e >> 7, rem = e & 127;
        const int kt2 = rem >> 3, nt2 = rem & 7;
        const float* src =
            (job==3) ? cao : (job==7) ? cgo :
            (job< 3) ? cai + (size_t)job*512*512 : cgi + (size_t)(job-4)*512*512;
        const size_t tile = (size_t)job*ATT_PLANE + ((size_t)kt2*NT_ATT + nt2)*2048;
        const int n = tid >> 2, k8 = (tid & 3)*8;
        const float* sp = src + (size_t)(nt2*64 + n)*512 + kt2*32 + k8;
        const f32x4 v0 = __builtin_nontemporal_load((const f32x4*)sp);
        const f32x4 v1 = __builtin_nontemporal_load((const f32x4*)(sp+4));
        const float f[8] = {v0[0],v0[1],v0[2],v0[3],v1[0],v1[1],v1[2],v1[3]};
        short8 h8, l8;
        #pragma unroll
        for (int q=0;q<8;q++){
            const unsigned short h = f2bh(f[q]);
            h8[q] = (short)h;
            l8[q] = (short)f2bh(f[q] - bh2f(h));
        }
        __builtin_nontemporal_store(h8, (short8*)(atth + tile + tid*8));
        __builtin_nontemporal_store(l8, (short8*)(attl + tile + tid*8));
        return;
    }

    // ---- transpose path ----
    const float* src; unsigned short *dh, *dl; int K, N, NT, nt, ktp;
    if (bid < 5920){
        const int plane = bid / 296, rem = bid % 296;
        const int s = plane & 1, layer = plane >> 1;
        src = (s ? winG : winS) + (size_t)layer*DM*DPROJ;
        dh = winh + (size_t)plane*WIN_PLANE;
        dl = winl + (size_t)plane*WIN_PLANE;
        K = DM; N = DPROJ; NT = NT_IN;
        nt = rem % 37; ktp = rem / 37;      // ktp in [0,8)
    } else {
        const int i = bid - 5920;
        const int plane = i / 128, rem = i % 128;
        const int s = plane & 1, layer = plane >> 1;
        src = (s ? woutG : woutS) + (size_t)layer*DIN*DM;
        dh = wouth + (size_t)plane*WOUT_PLANE;
        dl = woutl + (size_t)plane*WOUT_PLANE;
        K = DIN; N = DM; NT = NT_OUT;
        nt = rem % 8; ktp = rem / 8;        // ktp in [0,16)
    }

    __shared__ float tile[64][66];
    #pragma unroll
    for (int i=0;i<4;i++){
        const int kk = (tid>>4) + i*16;
        const int c4 = (tid&15)*4;
        const int n = nt*64 + c4;
        f32x4 v = {0.f,0.f,0.f,0.f};
        const float* sp = src + (size_t)(ktp*64+kk)*N + n;
        if (n + 3 < N) v = __builtin_nontemporal_load((const f32x4*)sp);
        else {
            if (n   < N) v[0] = sp[0];
            if (n+1 < N) v[1] = sp[1];
            if (n+2 < N) v[2] = sp[2];
            if (n+3 < N) v[3] = sp[3];
        }
        tile[kk][c4]=v[0]; tile[kk][c4+1]=v[1]; tile[kk][c4+2]=v[2]; tile[kk][c4+3]=v[3];
    }
    __syncthreads();

    const int n_l = tid >> 2, k8 = (tid & 3)*8;
    #pragma unroll
    for (int i=0;i<2;i++){
        const int kt2 = ktp*2 + i;
        short8 h8, l8;
        #pragma unroll
        for (int q=0;q<8;q++){
            const float f = tile[i*32 + k8 + q][n_l];
            const unsigned short h = f2bh(f);
            h8[q] = (short)h;
            l8[q] = (short)f2bh(f - bh2f(h));
        }
        const size_t off = ((size_t)kt2*NT + nt)*2048 + tid*8;
        __builtin_nontemporal_store(h8, (short8*)(dh + off));
        __builtin_nontemporal_store(l8, (short8*)(dl + off));
    }
}

// ---------------- split-K MFMA GEMM, pre-split bf16; W in tiled layout ----------------
struct GemmJob {
    const unsigned short* Ah; const unsigned short* Al;   // activations [M][K]
    const unsigned short* Wh; const unsigned short* Wl;   // tiled planes
    float* part; int M;
};

template<int NSPLIT>
__global__ __launch_bounds__(256) void gemm_mfma(GemmJob j0, GemmJob j1, GemmJob j2,
                                                 int N, int K, int NT)
{
    const int z = blockIdx.z;
    const int job = z / NSPLIT, split = z % NSPLIT;
    GemmJob jb = (job==0) ? j0 : (job==1 ? j1 : j2);
    const int bm = blockIdx.y*64, bn64 = blockIdx.x;
    const int M = jb.M;
    if (bm >= M) return;

    constexpr int SR = 40;
    __shared__ unsigned short AhS[2][64*SR], AlS[2][64*SR];
    __shared__ unsigned short BhS[2][64*SR], BlS[2][64*SR];

    const int tid = threadIdx.x;
    const int r0 = tid >> 2, k0off = (tid & 3)*8;
    const bool aok = (bm + r0 < M);
    const unsigned short* Aph = jb.Ah + (size_t)(bm+r0)*K;
    const unsigned short* Apl = jb.Al + (size_t)(bm+r0)*K;

    const int Kper = K / NSPLIT;
    const int koff = split * Kper;
    const int nk = Kper / 32;

    const size_t wbase = ((size_t)(koff >> 5)*NT + bn64)*2048 + (size_t)tid*8;
    const size_t wstep = (size_t)NT*2048;

    const short8 z8 = {0,0,0,0,0,0,0,0};
    short8 ra_h = z8, ra_l = z8, rw_h = z8, rw_l = z8;

    auto loadT = [&](int k0, int tstep){
        if (aok){
            ra_h = *(const short8*)(Aph + k0 + k0off);
            ra_l = *(const short8*)(Apl + k0 + k0off);
        } else { ra_h = z8; ra_l = z8; }
        rw_h = *(const short8*)(jb.Wh + wbase + (size_t)tstep*wstep);
        rw_l = *(const short8*)(jb.Wl + wbase + (size_t)tstep*wstep);
    };
    auto storeT = [&](int buf){
        *(short8*)&AhS[buf][r0*SR + k0off] = ra_h;
        *(short8*)&AlS[buf][r0*SR + k0off] = ra_l;
        *(short8*)&BhS[buf][r0*SR + k0off] = rw_h;
        *(short8*)&BlS[buf][r0*SR + k0off] = rw_l;
    };

    const int l = tid & 63, w = tid >> 6;
    const int fr = l & 15, kg = (l >> 4)*8;

    f32x4 acc0 = {0.f,0.f,0.f,0.f};
    f32x4 acc1 = {0.f,0.f,0.f,0.f};
    f32x4 acc2 = {0.f,0.f,0.f,0.f};
    f32x4 acc3 = {0.f,0.f,0.f,0.f};

    loadT(koff, 0);
    storeT(0);
    __syncthreads();
    for (int t=0; t<nk; ++t){
        const int cur = t & 1;
        if (t+1 < nk) loadT(koff + (t+1)*32, t+1);

        const short8 ah = *(const short8*)&AhS[cur][(w*16+fr)*SR + kg];
        const short8 al = *(const short8*)&AlS[cur][(w*16+fr)*SR + kg];
        {
            const short8 bh = *(const short8*)&BhS[cur][(fr)*SR + kg];
            const short8 bl = *(const short8*)&BlS[cur][(fr)*SR + kg];
            acc0 = __builtin_amdgcn_mfma_f32_16x16x32_bf16(ah, bh, acc0, 0,0,0);
            acc0 = __builtin_amdgcn_mfma_f32_16x16x32_bf16(ah, bl, acc0, 0,0,0);
            acc0 = __builtin_amdgcn_mfma_f32_16x16x32_bf16(al, bh, acc0, 0,0,0);
        }
        {
            const short8 bh = *(const short8*)&BhS[cur][(16+fr)*SR + kg];
            const short8 bl = *(const short8*)&BlS[cur][(16+fr)*SR + kg];
            acc1 = __builtin_amdgcn_mfma_f32_16x16x32_bf16(ah, bh, acc1, 0,0,0);
            acc1 = __builtin_amdgcn_mfma_f32_16x16x32_bf16(ah, bl, acc1, 0,0,0);
            acc1 = __builtin_amdgcn_mfma_f32_16x16x32_bf16(al, bh, acc1, 0,0,0);
        }
        {
            const short8 bh = *(const short8*)&BhS[cur][(32+fr)*SR + kg];
            const short8 bl = *(const short8*)&BlS[cur][(32+fr)*SR + kg];
            acc2 = __builtin_amdgcn_mfma_f32_16x16x32_bf16(ah, bh, acc2, 0,0,0);
            acc2 = __builtin_amdgcn_mfma_f32_16x16x32_bf16(ah, bl, acc2, 0,0,0);
            acc2 = __builtin_amdgcn_mfma_f32_16x16x32_bf16(al, bh, acc2, 0,0,0);
        }
        {
            const short8 bh = *(const short8*)&BhS[cur][(48+fr)*SR + kg];
            const short8 bl = *(const short8*)&BlS[cur][(48+fr)*SR + kg];
            acc3 = __builtin_amdgcn_mfma_f32_16x16x32_bf16(ah, bh, acc3, 0,0,0);
            acc3 = __builtin_amdgcn_mfma_f32_16x16x32_bf16(ah, bl, acc3, 0,0,0);
            acc3 = __builtin_amdgcn_mfma_f32_16x16x32_bf16(al, bh, acc3, 0,0,0);
        }
        if (t+1 < nk) storeT(cur^1);
        __syncthreads();
    }

    // C/D layout (m89-verified): col = lane&15, row = (lane>>4)*4 + reg
    float* __restrict__ P = jb.part + (size_t)split*M*N;
    const int rbase = bm + w*16 + (l>>4)*4;
    const int bn = bn64*64;
    #pragma unroll
    for (int nt=0; nt<4; ++nt){
        const f32x4 a = (nt==0)?acc0 : (nt==1)?acc1 : (nt==2)?acc2 : acc3;
        const int n = bn + nt*16 + fr;
        if (n < N){
            #pragma unroll
            for (int j=0;j<4;j++){
                const int m = rbase + j;
                if (m < M) P[(size_t)m*N + n] = a[j];
            }
        }
    }
}

// ---------------- reduce partials (+bias, +res, +optional bf16 planes) ----------------
struct RJob { const float* part; const float* bias; const float* res; float* C;
              unsigned short* ph; unsigned short* pl; int M; };

template<int NS>
__global__ __launch_bounds__(256) void reduce_k(RJob j0, RJob j1, int N)
{
    RJob j = blockIdx.y ? j1 : j0;
    const size_t total = (size_t)j.M*N;
    const size_t i4 = ((size_t)blockIdx.x*256 + threadIdx.x)*4;
    if (i4 >= total) return;
    float4 s = *(const float4*)(j.part + i4);
    #pragma unroll
    for (int t=1;t<NS;t++){
        const float4 v = *(const float4*)(j.part + (size_t)t*total + i4);
        s.x+=v.x; s.y+=v.y; s.z+=v.z; s.w+=v.w;
    }
    const int n = (int)(i4 % (size_t)N);
    if (j.bias){ s.x+=j.bias[n]; s.y+=j.bias[n+1]; s.z+=j.bias[n+2]; s.w+=j.bias[n+3]; }
    if (j.res){ const float4 r = *(const float4*)(j.res + i4); s.x+=r.x; s.y+=r.y; s.z+=r.z; s.w+=r.w; }
    if (j.C) *(float4*)(j.C + i4) = s;
    if (j.ph){
        const float f[4] = {s.x, s.y, s.z, s.w};
        short4_ h4, l4;
        #pragma unroll
        for (int q=0;q<4;q++){
            const unsigned short h = f2bh(f[q]);
            h4[q] = (short)h;
            l4[q] = (short)f2bh(f[q] - bh2f(h));
        }
        *(short4_*)(j.ph + i4) = h4;
        *(short4_*)(j.pl + i4) = l4;
    }
}

// ---------------- mamba prep: reduce 2 partials + conv + silu + softplus ----------------
struct PrepJob {
    const float* part;     // [SP_IN][R][DPROJ]
    float* xh; float* Bc; float* Cc; float* dtw;
    const float* cw; const float* cb; const float* dtb;
    int R, L;
};

__device__ __forceinline__ float4 psum2(const float* p, size_t pstr){
    float4 a = *(const float4*)p;
    const float4 b = *(const float4*)(p + pstr);
    a.x += b.x; a.y += b.y; a.z += b.z; a.w += b.w;
    return a;
}

__global__ __launch_bounds__(256) void mamba_prep(PrepJob js, PrepJob jg)
{
    PrepJob j = blockIdx.y ? jg : js;
    const int R = j.R, L = j.L;
    constexpr int QPR = 324;   // 320 (conv) + 4 (dt) quads per row
    const int q = blockIdx.x*256 + threadIdx.x;
    if (q >= R*QPR) return;
    const int r = q / QPR, qi = q % QPR;
    const int l = r % L;
    const size_t pstr = (size_t)R*DPROJ;
    const float* base = j.part + (size_t)r*DPROJ;

    if (qi < 320) {                 // ---- conv region
        const int cc = qi*4;        // 0..1276
        float tk[4][4];
        #pragma unroll
        for (int k=0;k<4;k++){
            const int lr = l - 3 + k;
            if (lr >= 0){
                float4 v = psum2(j.part + (size_t)(r-3+k)*DPROJ + 1024 + cc, pstr);
                tk[k][0]=v.x; tk[k][1]=v.y; tk[k][2]=v.z; tk[k][3]=v.w;
            } else {
                tk[k][0]=0.f; tk[k][1]=0.f; tk[k][2]=0.f; tk[k][3]=0.f;
            }
        }
        const float4 cb4 = *(const float4*)(j.cb + cc);
        const float cba[4] = {cb4.x, cb4.y, cb4.z, cb4.w};
        float out[4];
        #pragma unroll
        for (int jj=0;jj<4;jj++){
            const float4 wv = *(const float4*)(j.cw + (size_t)(cc+jj)*4);
            float v = cba[jj] + wv.x*tk[0][jj] + wv.y*tk[1][jj]
                              + wv.z*tk[2][jj] + wv.w*tk[3][jj];
            out[jj] = siluf(v);
        }
        float4 o4; o4.x=out[0]; o4.y=out[1]; o4.z=out[2]; o4.w=out[3];
        if (cc < 1024)       *(float4*)(j.xh + (size_t)r*1024 + cc)        = o4;
        else if (cc < 1152)  *(float4*)(j.Bc + (size_t)r*128 + (cc-1024))  = o4;
        else                 *(float4*)(j.Cc + (size_t)r*128 + (cc-1152))  = o4;
    } else {                        // ---- dt region
        const int hd = (qi-320)*4;  // 0,4,8,12
        float4 s = psum2(base + 2304 + hd, pstr);
        const float4 b4 = *(const float4*)(j.dtb + hd);
        float raw[4] = {s.x+b4.x, s.y+b4.y, s.z+b4.z, s.w+b4.w};
        float4 o4;
        float* op = &o4.x;
        #pragma unroll
        for (int jj=0;jj<4;jj++)
            op[jj] = (raw[jj] > 20.f) ? raw[jj] : log1pf(expf(raw[jj]));
        *(float4*)(j.dtw + (size_t)r*16 + hd) = o4;
    }
}

// ---------------- fused: G = decay .* (C @ B^T); Y = G @ X + D*X per (head,batch,stack) ----------------
__global__ __launch_bounds__(256) void mamba_y(
    const float* __restrict__ Bc_s, const float* __restrict__ Cc_s,
    const float* __restrict__ xh_s, const float* __restrict__ dtw_s,
    const float* __restrict__ al_s, const float* __restrict__ Dw_s, float* __restrict__ y_s,
    const float* __restrict__ Bc_g, const float* __restrict__ Cc_g,
    const float* __restrict__ xh_g, const float* __restrict__ dtw_g,
    const float* __restrict__ al_g, const float* __restrict__ Dw_g, float* __restrict__ y_g)
{
    const int h = blockIdx.x, b = blockIdx.y, st = blockIdx.z;
    const float* Bc  = st ? Bc_g  : Bc_s;
    const float* Cc  = st ? Cc_g  : Cc_s;
    const float* xh  = st ? xh_g  : xh_s;
    const float* dtw = st ? dtw_g : dtw_s;
    const float* al  = st ? al_g  : al_s;
    const float* Dw  = st ? Dw_g  : Dw_s;
    float* y = st ? y_g : y_s;
    const int L = st ? LG : LS;

    const int t = threadIdx.x;
    constexpr int SB = 132, SG = 60, SX = 68;
    __shared__ float Bm[64*SB], Cm[64*SB];
    __shared__ float Gm[64*SG], Xm[64*SX];
    __shared__ float dts[64], sps[64];

    const float Ah = -expf(al[h]);
    const float Dh = Dw[h];

    // dt + prefix scan (wave 0)
    if (t < 64){
        float dtv = (t < L) ? dtw[(size_t)(b*L+t)*16 + h] : 0.f;
        float s = dtv;
        #pragma unroll
        for (int d=1; d<64; d<<=1){
            float o = __shfl_up(s, d, 64);
            if (t >= d) s += o;
        }
        dts[t] = dtv; sps[t] = s;
    }
    // stage B, C, X tiles
    for (int idx = t; idx < L*32; idx += 256){
        const int l = idx >> 5, c4 = (idx & 31)*4;
        *(float4*)&Bm[l*SB + c4] = *(const float4*)(Bc + (size_t)(b*L+l)*128 + c4);
        *(float4*)&Cm[l*SB + c4] = *(const float4*)(Cc + (size_t)(b*L+l)*128 + c4);
    }
    for (int idx = t; idx < L*16; idx += 256){
        const int l = idx >> 4, c4 = (idx & 15)*4;
        *(float4*)&Xm[l*SX + c4] = *(const float4*)(xh + (size_t)(b*L+l)*1024 + h*64 + c4);
    }
    __syncthreads();

    const int ti = t >> 4, tj = t & 15;

    // G = decay .* (C @ B^T), computed in-block
    {
        float acc[4][4] = {};
        for (int k0=0;k0<128;k0+=4){
            float4 cr[4], br[4];
            #pragma unroll
            for (int a=0;a<4;a++) cr[a] = *(const float4*)&Cm[(ti+16*a)*SB + k0];
            #pragma unroll
            for (int qq=0;qq<4;qq++) br[qq] = *(const float4*)&Bm[(tj+16*qq)*SB + k0];
            #pragma unroll
            for (int a=0;a<4;a++)
                #pragma unroll
                for (int qq=0;qq<4;qq++)
                    acc[a][qq] += cr[a].x*br[qq].x + cr[a].y*br[qq].y
                                + cr[a].z*br[qq].z + cr[a].w*br[qq].w;
        }
        #pragma unroll
        for (int a=0;a<4;a++){
            const int i = ti + 16*a;
            if (i < L){
                const float si = sps[i];
                #pragma unroll
                for (int qq=0;qq<4;qq++){
                    const int jj = tj + 16*qq;
                    if (jj < L){
                        float gg = 0.f;
                        if (jj <= i)
                            gg = expf(Ah*(si - sps[jj])) * dts[jj] * acc[a][qq];
                        Gm[i*SG + jj] = gg;
                    }
                }
            }
        }
    }
    __syncthreads();

    // Y = G @ X + D*X
    int la[4];
    #pragma unroll
    for (int a=0;a<4;a++) la[a] = ti + 16*a;
    float accY[4][4] = {};
    for (int m=0; m<L; ++m){
        float xr[4], gr[4];
        #pragma unroll
        for (int qq=0;qq<4;qq++) xr[qq] = Xm[m*SX + tj + 16*qq];
        #pragma unroll
        for (int a=0;a<4;a++) gr[a] = (la[a] < L) ? Gm[la[a]*SG + m] : 0.f;
        #pragma unroll
        for (int a=0;a<4;a++)
            #pragma unroll
            for (int qq=0;qq<4;qq++) accY[a][qq] = fmaf(gr[a], xr[qq], accY[a][qq]);
    }
    #pragma unroll
    for (int a=0;a<4;a++){
        if (la[a] < L){
            float* yrow = y + (size_t)(b*L + la[a])*DIN + h*HD;
            #pragma unroll
            for (int qq=0;qq<4;qq++){
                const int col = tj + 16*qq;
                yrow[col] = accY[a][qq] + Dh * Xm[la[a]*SX + col];
            }
        }
    }
}

// ---------------- gated RMSNorm: silu(z) from in-proj partials, -> bf16 planes ----------------
__global__ __launch_bounds__(256) void gated_rmsnorm(
    const float* __restrict__ y_s, const float* __restrict__ part_s, const float* __restrict__ nw_s,
    unsigned short* __restrict__ oh_s, unsigned short* __restrict__ ol_s,
    const float* __restrict__ y_g, const float* __restrict__ part_g, const float* __restrict__ nw_g,
    unsigned short* __restrict__ oh_g, unsigned short* __restrict__ ol_g)
{
    int r = blockIdx.x, t = threadIdx.x;
    int st = (r >= RS);
    int row = st ? r - RS : r;
    const float* y  = (st ? y_g  : y_s) + (size_t)row*DIN;
    const float* zp = (st ? part_g : part_s) + (size_t)row*DPROJ;
    const size_t pstr = (size_t)(st ? RG : RS)*DPROJ;
    const float* nw = st ? nw_g : nw_s;
    unsigned short* oh = (st ? oh_g : oh_s) + (size_t)row*DIN;
    unsigned short* ol = (st ? ol_g : ol_s) + (size_t)row*DIN;

    float g[4]; float s2 = 0.f;
    #pragma unroll
    for (int i=0;i<4;i++){
        int idx = t + i*256;
        const float zv = zp[idx] + zp[pstr + idx];
        float gv = y[idx] * siluf(zv);
        g[i] = gv; s2 += gv*gv;
    }
    #pragma unroll
    for (int o2=32;o2;o2>>=1) s2 += __shfl_xor(s2, o2, 64);
    __shared__ float red[4];
    if ((t & 63) == 0) red[t>>6] = s2;
    __syncthreads();
    float S2 = red[0]+red[1]+red[2]+red[3];
    float scale = rsqrtf(S2*(1.f/DIN) + 1e-5f);
    #pragma unroll
    for (int i=0;i<4;i++){
        int idx = t + i*256;
        const float val = g[i]*scale*nw[idx];
        const unsigned short h = f2bh(val);
        oh[idx] = h;
        ol[idx] = f2bh(val - bh2f(h));
    }
}

// ---------------- LayerNorm rows -> bf16 planes ----------------
__global__ __launch_bounds__(256) void ln_rows(
    const float* __restrict__ x, const float* __restrict__ w, const float* __restrict__ b,
    unsigned short* __restrict__ outh, unsigned short* __restrict__ outl, int D)
{
    int r = blockIdx.x, t = threadIdx.x;
    const float* xr = x + (size_t)r*D;
    float s = 0.f, s2 = 0.f;
    for (int i=t;i<D;i+=256){ float v = xr[i]; s += v; s2 += v*v; }
    #pragma unroll
    for (int o=32;o;o>>=1){ s += __shfl_xor(s,o,64); s2 += __shfl_xor(s2,o,64); }
    __shared__ float red[8];
    if ((t & 63) == 0){ red[t>>6] = s; red[4+(t>>6)] = s2; }
    __syncthreads();
    float S  = red[0]+red[1]+red[2]+red[3];
    float S2 = red[4]+red[5]+red[6]+red[7];
    float mean = S/D;
    float var  = S2/D - mean*mean;
    float inv  = rsqrtf(var + 1e-5f);
    for (int i=t;i<D;i+=256){
        const float val = (xr[i]-mean)*inv*w[i] + b[i];
        const unsigned short h = f2bh(val);
        outh[(size_t)r*D + i] = h;
        outl[(size_t)r*D + i] = f2bh(val - bh2f(h));
    }
}

// ---------------- cross-attention core: split-K partials + bias in, bf16 planes out ----------------
template<int LQ, int LKV, int NS>
__global__ __launch_bounds__(256) void mha_attn2(
    const float* __restrict__ pq, const float* __restrict__ pk, const float* __restrict__ pv,
    const float* __restrict__ qb, const float* __restrict__ kb, const float* __restrict__ vb,
    int Mq, int Mkv,
    unsigned short* __restrict__ outh, unsigned short* __restrict__ outl)
{
    const int hh = blockIdx.x, b = blockIdx.y, t = threadIdx.x;
    const size_t strQ = (size_t)Mq*DM, strKV = (size_t)Mkv*DM;
    constexpr int SD = 68;
    constexpr int SS = 60;
    constexpr int QT = (LQ +15)/16;
    constexpr int KT = (LKV+15)/16;
    __shared__ float Qs[LQ*SD];
    __shared__ float Ks[LKV*SD];
    __shared__ float Vs[LKV*SD];
    __shared__ float Ps[LQ*SS];

    for (int idx = t; idx < LQ*16; idx += 256){
        const int r = idx>>4, c4 = (idx&15)*4;
        float4 v = *(const float4*)(qb + hh*64 + c4);
        const size_t off = (size_t)(b*LQ+r)*DM + hh*64 + c4;
        #pragma unroll
        for (int s=0;s<NS;s++){
            const float4 u = *(const float4*)(pq + s*strQ + off);
            v.x+=u.x; v.y+=u.y; v.z+=u.z; v.w+=u.w;
        }
        *(float4*)&Qs[r*SD+c4] = v;
    }
    for (int idx = t; idx < LKV*16; idx += 256){
        const int r = idx>>4, c4 = (idx&15)*4;
        float4 kv = *(const float4*)(kb + hh*64 + c4);
        float4 vv = *(const float4*)(vb + hh*64 + c4);
        const size_t off = (size_t)(b*LKV+r)*DM + hh*64 + c4;
        #pragma unroll
        for (int s=0;s<NS;s++){
            const float4 ku = *(const float4*)(pk + s*strKV + off);
            const float4 vu = *(const float4*)(pv + s*strKV + off);
            kv.x+=ku.x; kv.y+=ku.y; kv.z+=ku.z; kv.w+=ku.w;
            vv.x+=vu.x; vv.y+=vu.y; vv.z+=vu.z; vv.w+=vu.w;
        }
        *(float4*)&Ks[r*SD+c4] = kv;
        *(float4*)&Vs[r*SD+c4] = vv;
    }
    __syncthreads();

    const int ti = t>>4, tj = t&15;

    {
        float acc[QT][KT];
        #pragma unroll
        for (int a=0;a<QT;a++)
            #pragma unroll
            for (int q=0;q<KT;q++) acc[a][q] = 0.f;
        for (int k0=0;k0<64;k0+=4){
            float4 qr[QT], kr[KT];
            #pragma unroll
            for (int a=0;a<QT;a++){
                int rr = ti+16*a; if (rr >= LQ) rr = LQ-1;
                qr[a] = *(const float4*)&Qs[rr*SD+k0];
            }
            #pragma unroll
            for (int q=0;q<KT;q++){
                int rr = tj+16*q; if (rr >= LKV) rr = LKV-1;
                kr[q] = *(const float4*)&Ks[rr*SD+k0];
            }
            #pragma unroll
            for (int a=0;a<QT;a++)
                #pragma unroll
                for (int q=0;q<KT;q++)
                    acc[a][q] += qr[a].x*kr[q].x + qr[a].y*kr[q].y
                               + qr[a].z*kr[q].z + qr[a].w*kr[q].w;
        }
        #pragma unroll
        for (int a=0;a<QT;a++){
            const int i = ti+16*a;
            if (i < LQ){
                #pragma unroll
                for (int q=0;q<KT;q++){
                    const int jj = tj+16*q;
                    if (jj < LKV) Ps[i*SS+jj] = acc[a][q]*0.125f;
                }
            }
        }
    }
    __syncthreads();

    if (t < LQ){
        float mx = -1e30f;
        for (int j=0;j<LKV;j++) mx = fmaxf(mx, Ps[t*SS+j]);
        float se = 0.f;
        for (int j=0;j<LKV;j++){ float e = expf(Ps[t*SS+j]-mx); Ps[t*SS+j] = e; se += e; }
        const float inv = 1.f/se;
        for (int j=0;j<LKV;j++) Ps[t*SS+j] *= inv;
    }
    __syncthreads();

    {
        float o[QT][4];
        #pragma unroll
        for (int a=0;a<QT;a++){ o[a][0]=0.f; o[a][1]=0.f; o[a][2]=0.f; o[a][3]=0.f; }
        for (int m=0;m<LKV;m++){
            const float4 vv = *(const float4*)&Vs[m*SD + tj*4];
            #pragma unroll
            for (int a=0;a<QT;a++){
                const int rr = ti+16*a;
                const float pv2 = (rr < LQ) ? Ps[rr*SS+m] : 0.f;
                o[a][0] = fmaf(pv2, vv.x, o[a][0]);
                o[a][1] = fmaf(pv2, vv.y, o[a][1]);
                o[a][2] = fmaf(pv2, vv.z, o[a][2]);
                o[a][3] = fmaf(pv2, vv.w, o[a][3]);
            }
        }
        #pragma unroll
        for (int a=0;a<QT;a++){
            const int rr = ti+16*a;
            if (rr < LQ){
                short4_ h4, l4;
                #pragma unroll
                for (int q=0;q<4;q++){
                    const unsigned short h = f2bh(o[a][q]);
                    h4[q] = (short)h;
                    l4[q] = (short)f2bh(o[a][q] - bh2f(h));
                }
                const size_t off = (size_t)(b*LQ+rr)*DM + hh*64 + tj*4;
                *(short4_*)(outh + off) = h4;
                *(short4_*)(outl + off) = l4;
            }
        }
    }
}

// ---------------- fused head: meanpool + LN + classifier ----------------
__global__ __launch_bounds__(512) void head_fused(
    const float* __restrict__ xs, const float* __restrict__ xg,
    const float* __restrict__ lw, const float* __restrict__ lb,
    const float* __restrict__ cw, const float* __restrict__ cb,
    float* __restrict__ out)
{
    const int b = blockIdx.x, t = threadIdx.x;
    __shared__ float fr[1024];
    __shared__ float red[16];
    __shared__ float pr[55*8];
    {
        float s = 0.f;
        for (int l=0;l<LS;l++) s += xs[(size_t)(b*LS+l)*DM + t];
        fr[t] = s*(1.f/LS);
        float g = 0.f;
        for (int l=0;l<LG;l++) g += xg[(size_t)(b*LG+l)*DM + t];
        fr[512+t] = g*(1.f/LG);
    }
    __syncthreads();
    float v0 = fr[t], v1 = fr[512+t];
    float sm = v0+v1, sq = v0*v0 + v1*v1;
    #pragma unroll
    for (int o=32;o;o>>=1){ sm += __shfl_xor(sm,o,64); sq += __shfl_xor(sq,o,64); }
    if ((t&63)==0){ red[t>>6] = sm; red[8+(t>>6)] = sq; }
    __syncthreads();
    float S=0.f, Q=0.f;
    #pragma unroll
    for (int i=0;i<8;i++){ S += red[i]; Q += red[8+i]; }
    const float mean = S*(1.f/1024.f);
    const float var  = Q*(1.f/1024.f) - mean*mean;
    const float inv  = rsqrtf(var + 1e-5f);
    fr[t]     = (v0-mean)*inv*lw[t]     + lb[t];
    fr[512+t] = (v1-mean)*inv*lw[512+t] + lb[512+t];
    __syncthreads();
    {
        const int c = t & 63, pp = t >> 6;
        if (c < 55){
            float a = 0.f;
            const float* wr = cw + (size_t)c*1024 + pp*128;
            const float* xr = fr + pp*128;
            #pragma unroll 4
            for (int k=0;k<128;k++) a = fmaf(xr[k], wr[k], a);
            pr[c*8+pp] = a;
        }
    }
    __syncthreads();
    if (t < 55){
        float a = cb[t];
        #pragma unroll
        for (int p2=0;p2<8;p2++) a += pr[t*8+p2];
        out[b*55 + t] = a;
    }
}

// ---------------- launch ----------------
extern "C" void kernel_launch(void* const* d_in, const int* in_sizes, int n_in,
                              void* d_out, int out_size, void* d_ws, size_t ws_size,
                              hipStream_t stream)
{
    (void)in_sizes; (void)n_in; (void)out_size; (void)ws_size;
    const float* x_spectra = (const float*)d_in[0];
    const float* x_gaia    = (const float*)d_in[1];
    const float* tok_w_s   = (const float*)d_in[2];
    const float* tok_b_s   = (const float*)d_in[3];
    const float* tok_w_g   = (const float*)d_in[4];
    const float* tok_b_g   = (const float*)d_in[5];
    const float* ms_Win    = (const float*)d_in[6];
    const float* ms_conv_w = (const float*)d_in[7];
    const float* ms_conv_b = (const float*)d_in[8];
    const float* ms_dtb    = (const float*)d_in[9];
    const float* ms_Alog   = (const float*)d_in[10];
    const float* ms_D      = (const float*)d_in[11];
    const float* ms_nw     = (const float*)d_in[12];
    const float* ms_Wout   = (const float*)d_in[13];
    const float* mg_Win    = (const float*)d_in[14];
    const float* mg_conv_w = (const float*)d_in[15];
    const float* mg_conv_b = (const float*)d_in[16];
    const float* mg_dtb    = (const float*)d_in[17];
    const float* mg_Alog   = (const float*)d_in[18];
    const float* mg_D      = (const float*)d_in[19];
    const float* mg_nw     = (const float*)d_in[20];
    const float* mg_Wout   = (const float*)d_in[21];
    const float* cas_ln_w  = (const float*)d_in[22];
    const float* cas_ln_b  = (const float*)d_in[23];
    const float* cas_in_w  = (const float*)d_in[24];
    const float* cas_in_b  = (const float*)d_in[25];
    const float* cas_out_w = (const float*)d_in[26];
    const float* cas_out_b = (const float*)d_in[27];
    const float* cag_ln_w  = (const float*)d_in[28];
    const float* cag_ln_b  = (const float*)d_in[29];
    const float* cag_in_w  = (const float*)d_in[30];
    const float* cag_in_b  = (const float*)d_in[31];
    const float* cag_out_w = (const float*)d_in[32];
    const float* cag_out_b = (const float*)d_in[33];
    const float* cls_ln_w  = (const float*)d_in[34];
    const float* cls_ln_b  = (const float*)d_in[35];
    const float* cls_w     = (const float*)d_in[36];
    const float* cls_b     = (const float*)d_in[37];

    float* p = (float*)d_ws;
    auto alloc = [&](size_t n){ float* r = p; p += n; return r; };
    float* xs       = alloc((size_t)RS*DM);
    float* xg       = alloc((size_t)RG*DM);
    float* y_s      = alloc((size_t)RS*DIN);
    float* y_g      = alloc((size_t)RG*DIN);
    float* part_inS  = alloc((size_t)SP_IN*RS*DPROJ);
    float* part_inG  = alloc((size_t)SP_IN*RG*DPROJ);
    float* part_outS = alloc((size_t)SP_OUT*RS*DM);
    float* part_outG = alloc((size_t)SP_OUT*RG*DM);
    float* part_q    = alloc((size_t)SP_ATT*RS*DM);
    float* part_k    = alloc((size_t)SP_ATT*RS*DM);
    float* part_v    = alloc((size_t)SP_ATT*RS*DM);
    float* xh_s    = alloc((size_t)RS*1024);
    float* xh_g    = alloc((size_t)RG*1024);
    float* Bc_s    = alloc((size_t)RS*128);
    float* Bc_g    = alloc((size_t)RG*128);
    float* Cc_s    = alloc((size_t)RS*128);
    float* Cc_g    = alloc((size_t)RG*128);
    float* dtw_s   = alloc((size_t)RS*16);
    float* dtw_g   = alloc((size_t)RG*16);

    unsigned short* up = (unsigned short*)p;
    auto ualloc = [&](size_t n){ unsigned short* r = up; up += n; return r; };
    unsigned short* xsh   = ualloc((size_t)RS*DM);
    unsigned short* xsl   = ualloc((size_t)RS*DM);
    unsigned short* xgh   = ualloc((size_t)RG*DM);
    unsigned short* xgl   = ualloc((size_t)RG*DM);
    unsigned short* ynh_s = ualloc((size_t)RS*DIN);
    unsigned short* ynl_s = ualloc((size_t)RS*DIN);
    unsigned short* ynh_g = ualloc((size_t)RG*DIN);
    unsigned short* ynl_g = ualloc((size_t)RG*DIN);
    unsigned short* lnh   = ualloc((size_t)RS*DM);
    unsigned short* lnl   = ualloc((size_t)RS*DM);
    unsigned short* aoh   = ualloc((size_t)RS*DM);
    unsigned short* aol   = ualloc((size_t)RS*DM);
    unsigned short* atth  = ualloc((size_t)8*ATT_PLANE);
    unsigned short* attl  = ualloc((size_t)8*ATT_PLANE);
    unsigned short* winh  = ualloc((size_t)20*WIN_PLANE);
    unsigned short* winl  = ualloc((size_t)20*WIN_PLANE);
    unsigned short* wouth = ualloc((size_t)20*WOUT_PLANE);
    unsigned short* woutl = ualloc((size_t)20*WOUT_PLANE);

    // tiled attention plane bases: q,k,v,o for cas (0..3) and cag (4..7)
    unsigned short* casq_h = atth + 0*ATT_PLANE; unsigned short* casq_l = attl + 0*ATT_PLANE;
    unsigned short* cask_h = atth + 1*ATT_PLANE; unsigned short* cask_l = attl + 1*ATT_PLANE;
    unsigned short* casv_h = atth + 2*ATT_PLANE; unsigned short* casv_l = attl + 2*ATT_PLANE;
    unsigned short* caso_h = atth + 3*ATT_PLANE; unsigned short* caso_l = attl + 3*ATT_PLANE;
    unsigned short* cagq_h = atth + 4*ATT_PLANE; unsigned short* cagq_l = attl + 4*ATT_PLANE;
    unsigned short* cagk_h = atth + 5*ATT_PLANE; unsigned short* cagk_l = attl + 5*ATT_PLANE;
    unsigned short* cagv_h = atth + 6*ATT_PLANE; unsigned short* cagv_l = attl + 6*ATT_PLANE;
    unsigned short* cago_h = atth + 7*ATT_PLANE; unsigned short* cago_l = attl + 7*ATT_PLANE;

    // one-time weight conversion (tiled, NT loads/stores)
    convert_weights<<<dim3(9504), 256, 0, stream>>>(
        ms_Win, mg_Win, ms_Wout, mg_Wout,
        cas_in_w, cas_out_w, cag_in_w, cag_out_w,
        winh, winl, wouth, woutl, atth, attl);

    // tokenize (both modalities)
    tokenize2<<<dim3(LS, BB, 2), 512, 0, stream>>>(
        x_spectra, tok_w_s, tok_b_s, xs, xsh, xsl,
        x_gaia,    tok_w_g, tok_b_g, xg, xgh, xgl);

    const int rblkS = (RS*DM + 1023)/1024;   // 228
    const int prepBlk = (RS*324 + 255)/256;  // 578

    // mamba stacks
    for (int i=0;i<NLAY;i++){
        const float* cw_s   = ms_conv_w + (size_t)i*1280*4;
        const float* cw_g   = mg_conv_w + (size_t)i*1280*4;
        const float* cbv_s  = ms_conv_b + (size_t)i*1280;
        const float* cbv_g  = mg_conv_b + (size_t)i*1280;
        const float* dtb_s  = ms_dtb  + (size_t)i*NH;
        const float* dtb_g  = mg_dtb  + (size_t)i*NH;
        const float* al_s   = ms_Alog + (size_t)i*NH;
        const float* al_g   = mg_Alog + (size_t)i*NH;
        const float* Dw_s   = ms_D    + (size_t)i*NH;
        const float* Dw_g   = mg_D    + (size_t)i*NH;
        const float* nw_s   = ms_nw   + (size_t)i*DIN;
        const float* nw_g   = mg_nw   + (size_t)i*DIN;

        const unsigned short* wih_s = winh + (size_t)(2*i+0)*WIN_PLANE;
        const unsigned short* wil_s = winl + (size_t)(2*i+0)*WIN_PLANE;
        const unsigned short* wih_g = winh + (size_t)(2*i+1)*WIN_PLANE;
        const unsigned short* wil_g = winl + (size_t)(2*i+1)*WIN_PLANE;
        const unsigned short* woh_s = wouth + (size_t)(2*i+0)*WOUT_PLANE;
        const unsigned short* wol_s = woutl + (size_t)(2*i+0)*WOUT_PLANE;
        const unsigned short* woh_g = wouth + (size_t)(2*i+1)*WOUT_PLANE;
        const unsigned short* wol_g = woutl + (size_t)(2*i+1)*WOUT_PLANE;

        GemmJob inS{xsh, xsl, wih_s, wil_s, part_inS, RS};
        GemmJob inG{xgh, xgl, wih_g, wil_g, part_inG, RG};
        gemm_mfma<SP_IN><<<dim3(NT_IN, 8, 2*SP_IN), 256, 0, stream>>>(
            inS, inG, inG, DPROJ, DM, NT_IN);

        PrepJob pjS{part_inS, xh_s, Bc_s, Cc_s, dtw_s, cw_s, cbv_s, dtb_s, RS, LS};
        PrepJob pjG{part_inG, xh_g, Bc_g, Cc_g, dtw_g, cw_g, cbv_g, dtb_g, RG, LG};
        mamba_prep<<<dim3(prepBlk, 2), 256, 0, stream>>>(pjS, pjG);

        mamba_y<<<dim3(NH, BB, 2), 256, 0, stream>>>(
            Bc_s, Cc_s, xh_s, dtw_s, al_s, Dw_s, y_s,
            Bc_g, Cc_g, xh_g, dtw_g, al_g, Dw_g, y_g);

        gated_rmsnorm<<<dim3(RS+RG), 256, 0, stream>>>(
            y_s, part_inS, nw_s, ynh_s, ynl_s,  y_g, part_inG, nw_g, ynh_g, ynl_g);

        GemmJob outS{ynh_s, ynl_s, woh_s, wol_s, part_outS, RS};
        GemmJob outG{ynh_g, ynl_g, woh_g, wol_g, part_outG, RG};
        gemm_mfma<SP_OUT><<<dim3(NT_OUT, 8, 2*SP_OUT), 256, 0, stream>>>(
            outS, outG, outG, DM, DIN, NT_OUT);

        RJob roS{part_outS, nullptr, nullptr, xs, xsh, xsl, RS};
        RJob roG{part_outG, nullptr, nullptr, xg, xgh, xgl, RG};
        reduce_k<SP_OUT><<<dim3(rblkS, 2), 256, 0, stream>>>(roS, roG, DM);
    }

    // cross-attention: xs = xs + MHA(LN(xs), xg)
    {
        ln_rows<<<dim3(RS), 256, 0, stream>>>(xs, cas_ln_w, cas_ln_b, lnh, lnl, DM);
        GemmJob jq{lnh, lnl, casq_h, casq_l, part_q, RS};
        GemmJob jk{xgh, xgl, cask_h, cask_l, part_k, RG};
        GemmJob jv{xgh, xgl, casv_h, casv_l, part_v, RG};
        gemm_mfma<SP_ATT><<<dim3(NT_ATT, 8, 3*SP_ATT), 256, 0, stream>>>(jq, jk, jv, DM, DM, NT_ATT);
        mha_attn2<LS,LG,SP_ATT><<<dim3(8,BB), 256, 0, stream>>>(
            part_q, part_k, part_v, cas_in_b, cas_in_b+512, cas_in_b+1024, RS, RG, aoh, aol);
        GemmJob jo{aoh, aol, caso_h, caso_l, part_outS, RS};
        gemm_mfma<SP_ATT><<<dim3(NT_ATT, 8, SP_ATT), 256, 0, stream>>>(jo, jo, jo, DM, DM, NT_ATT);
        RJob ro{part_outS, cas_out_b, xs, xs, xsh, xsl, RS};
        reduce_k<SP_ATT><<<dim3(rblkS, 1), 256, 0, stream>>>(ro, ro, DM);
    }

    // cross-attention: xg = xg + MHA(LN(xg), xs_updated)
    {
        ln_rows<<<dim3(RG), 256, 0, stream>>>(xg, cag_ln_w, cag_ln_b, lnh, lnl, DM);
        GemmJob jq{lnh, lnl, cagq_h, cagq_l, part_q, RG};
        GemmJob jk{xsh, xsl, cagk_h, cagk_l, part_k, RS};
        GemmJob jv{xsh, xsl, cagv_h, cagv_l, part_v, RS};
        gemm_mfma<SP_ATT><<<dim3(NT_ATT, 8, 3*SP_ATT), 256, 0, stream>>>(jq, jk, jv, DM, DM, NT_ATT);
        mha_attn2<LG,LS,SP_ATT><<<dim3(8,BB), 256, 0, stream>>>(
            part_q, part_k, part_v, cag_in_b, cag_in_b+512, cag_in_b+1024, RG, RS, aoh, aol);
        GemmJob jo{aoh, aol, cago_h, cago_l, part_outS, RG};
        gemm_mfma<SP_ATT><<<dim3(NT_ATT, 2, SP_ATT), 256, 0, stream>>>(jo, jo, jo, DM, DM, NT_ATT);
        RJob ro{part_outS, cag_out_b, xg, xg, nullptr, nullptr, RG};
        reduce_k<SP_ATT><<<dim3((RG*DM+1023)/1024, 1), 256, 0, stream>>>(ro, ro, DM);
    }

    // fused head
    head_fused<<<dim3(BB), 512, 0, stream>>>(xs, xg, cls_ln_w, cls_ln_b, cls_w, cls_b, (float*)d_out);
}